// Round 1
// baseline (949.040 us; speedup 1.0000x reference)
//
#include <hip/hip_runtime.h>
#include <math.h>

#define N_TOK 2884
#define HW_IMG 576
#define NT_TOK 577
#define CDIM 768
#define NH 12
#define HD 64
#define QKV_COLS 2304

// ---------------- Kernel 1: QKV GEMM + bias + RoPE2D + SO3 epilogue ----------------
// grid (46 row tiles, 36 col tiles of 64 = one (which,head) chunk), 256 threads
__global__ __launch_bounds__(256)
void qkv_rope_so3(const float* __restrict__ q_tokens,
                  const float* __restrict__ t_tokens,
                  const float* __restrict__ pos2d,
                  const float* __restrict__ tposes,
                  const float* __restrict__ Wqkv,
                  const float* __restrict__ bqkv,
                  float* __restrict__ Qb,
                  float* __restrict__ Kb,
                  float* __restrict__ Vb)
{
    __shared__ __align__(16) float As[16][64];   // A chunk, stored transposed [k][row]
    __shared__ __align__(16) float Bs[16][64];   // W chunk [k][col]
    __shared__ float Ct[64][65];                 // output tile (padded for scalar access)

    const int rb = blockIdx.x;
    const int cb = blockIdx.y;          // 0..35
    const int which = cb / NH;          // 0=q 1=k 2=v
    const int h = cb - which * NH;
    const int colbase = cb * 64;
    const int tid = threadIdx.x;
    const int tx = tid & 15, ty = tid >> 4;

    // A staging map: one float4 per thread per chunk
    const int ar = tid >> 2;
    const int ak4 = (tid & 3) << 2;
    int agr = rb * 64 + ar;
    if (agr >= N_TOK) agr = N_TOK - 1;                 // clamp (stores guarded later)
    const float* arow = (agr < HW_IMG) ? (q_tokens + (size_t)agr * CDIM)
                                       : (t_tokens + (size_t)(agr - HW_IMG) * CDIM);
    // B staging map
    const int bk = tid >> 4;
    const int bc4 = (tid & 15) << 2;

    float acc[4][4];
    #pragma unroll
    for (int i = 0; i < 4; ++i) {
        #pragma unroll
        for (int j = 0; j < 4; ++j) acc[i][j] = 0.f;
    }

    for (int k0 = 0; k0 < CDIM; k0 += 16) {
        const float4 a4 = *(const float4*)(arow + k0 + ak4);
        const float4 b4 = *(const float4*)(Wqkv + (size_t)(k0 + bk) * QKV_COLS + colbase + bc4);
        __syncthreads();
        As[ak4 + 0][ar] = a4.x;
        As[ak4 + 1][ar] = a4.y;
        As[ak4 + 2][ar] = a4.z;
        As[ak4 + 3][ar] = a4.w;
        *(float4*)&Bs[bk][bc4] = b4;
        __syncthreads();
        #pragma unroll
        for (int kk = 0; kk < 16; ++kk) {
            const float4 av = *(const float4*)&As[kk][ty << 2];
            const float4 bv = *(const float4*)&Bs[kk][tx << 2];
            acc[0][0] += av.x * bv.x; acc[0][1] += av.x * bv.y; acc[0][2] += av.x * bv.z; acc[0][3] += av.x * bv.w;
            acc[1][0] += av.y * bv.x; acc[1][1] += av.y * bv.y; acc[1][2] += av.y * bv.z; acc[1][3] += av.y * bv.w;
            acc[2][0] += av.z * bv.x; acc[2][1] += av.z * bv.y; acc[2][2] += av.z * bv.z; acc[2][3] += av.z * bv.w;
            acc[3][0] += av.w * bv.x; acc[3][1] += av.w * bv.y; acc[3][2] += av.w * bv.z; acc[3][3] += av.w * bv.w;
        }
    }

    // bias + stash tile to LDS for cross-dim transforms
    #pragma unroll
    for (int i = 0; i < 4; ++i) {
        #pragma unroll
        for (int j = 0; j < 4; ++j) {
            Ct[(ty << 2) + i][(tx << 2) + j] = acc[i][j] + bqkv[colbase + (tx << 2) + j];
        }
    }
    __syncthreads();

    // transform + write: thread -> (row er, dim slice [16*eu, 16*eu+16))
    const int er = tid >> 2;
    const int eu = tid & 3;
    const int n = rb * 64 + er;
    if (n < N_TOK) {
        float outv[16];
        const bool is_img = (n < HW_IMG);
        int ts = 0, tj = 0;
        if (!is_img) { const int m = n - HW_IMG; ts = m / NT_TOK; tj = m - ts * NT_TOK; }

        if (which < 2 && is_img) {
            // RoPE2D: dims 0..31 use pos.y, 32..63 use pos.x; rotate-half within each 32-block
            const float p = (eu < 2) ? pos2d[2 * n] : pos2d[2 * n + 1];
            const bool lowhalf = ((eu & 1) == 0);
            #pragma unroll
            for (int dd = 0; dd < 16; ++dd) {
                const int d = (eu << 4) + dd;
                float sv, cv;
                sincosf(p * expf((float)dd * -0.28782313662425574f), &sv, &cv); // 100^(-dd/16)
                const float rot = lowhalf ? -Ct[er][d + 16] : Ct[er][d - 16];
                outv[dd] = Ct[er][d] * cv + rot * sv;
            }
        } else if (which < 2 && !is_img && tj < HW_IMG) {
            // SO3: rotate first 30 dims in triples by R = tposes[ts][:3][:3]
            #pragma unroll
            for (int dd = 0; dd < 16; ++dd) {
                const int d = (eu << 4) + dd;
                float val = Ct[er][d];
                if (d < 30) {
                    const int g = d / 3;
                    const float* R = tposes + ts * 16 + (d - g * 3) * 4;
                    val = R[0] * Ct[er][g * 3] + R[1] * Ct[er][g * 3 + 1] + R[2] * Ct[er][g * 3 + 2];
                }
                outv[dd] = val;
            }
        } else {
            #pragma unroll
            for (int dd = 0; dd < 16; ++dd) outv[dd] = Ct[er][(eu << 4) + dd];
        }

        float* dst = (which == 0 ? Qb : which == 1 ? Kb : Vb)
                   + ((size_t)h * N_TOK + n) * HD + (eu << 4);
        #pragma unroll
        for (int q4 = 0; q4 < 4; ++q4)
            *(float4*)(dst + (q4 << 2)) = make_float4(outv[q4 * 4 + 0], outv[q4 * 4 + 1],
                                                      outv[q4 * 4 + 2], outv[q4 * 4 + 3]);
    }
}

// ---------------- Kernel 2: fp32 flash attention ----------------
// grid (46 q-tiles, 12 heads), 256 threads: thread = (row r=tid>>2, dim/key slice u=tid&3)
__global__ __launch_bounds__(256)
void attn_fp32(const float* __restrict__ Qb, const float* __restrict__ Kb,
               const float* __restrict__ Vb, float* __restrict__ Ob)
{
    __shared__ __align__(16) float qsT[64][64];  // [d][row], XOR-swizzled cols
    __shared__ __align__(16) float ksT[64][64];  // [d][key], XOR-swizzled cols
    __shared__ __align__(16) float vsm[64][64];  // [key][d]

    const int h = blockIdx.y;
    const int qb = blockIdx.x;
    const int tid = threadIdx.x;
    const int r = tid >> 2;             // 0..63 q-row within tile
    const int u = tid & 3;
    const int cu = u << 4;              // dim / key slice base

    const float* Qh = Qb + (size_t)h * N_TOK * HD;
    const float* Kh = Kb + (size_t)h * N_TOK * HD;
    const float* Vh = Vb + (size_t)h * N_TOK * HD;

    // stage Q transposed (+swizzle), pre-scaled by 1/sqrt(64)
    for (int t = tid; t < 1024; t += 256) {
        const int rr = t >> 4, c4 = (t & 15) << 2;
        const int gr = qb * 64 + rr;
        float4 v4 = make_float4(0.f, 0.f, 0.f, 0.f);
        if (gr < N_TOK) v4 = *(const float4*)(Qh + (size_t)gr * HD + c4);
        qsT[c4 + 0][rr ^ ((((c4 + 0) >> 3) & 7) << 2)] = v4.x * 0.125f;
        qsT[c4 + 1][rr ^ ((((c4 + 1) >> 3) & 7) << 2)] = v4.y * 0.125f;
        qsT[c4 + 2][rr ^ ((((c4 + 2) >> 3) & 7) << 2)] = v4.z * 0.125f;
        qsT[c4 + 3][rr ^ ((((c4 + 3) >> 3) & 7) << 2)] = v4.w * 0.125f;
    }

    float m0 = -1e30f, l0 = 0.f;
    float acc[16];
    #pragma unroll
    for (int i = 0; i < 16; ++i) acc[i] = 0.f;

    const int NTILE = (N_TOK + 63) / 64;   // 46
    for (int kt = 0; kt < NTILE; ++kt) {
        const int kbase = kt << 6;
        __syncthreads();   // previous tile fully consumed
        for (int t = tid; t < 1024; t += 256) {
            const int j = t >> 4, c4 = (t & 15) << 2;
            const int gk = kbase + j;
            float4 kv = make_float4(0.f, 0.f, 0.f, 0.f), vv = kv;
            if (gk < N_TOK) {
                kv = *(const float4*)(Kh + (size_t)gk * HD + c4);
                vv = *(const float4*)(Vh + (size_t)gk * HD + c4);
            }
            ksT[c4 + 0][j ^ ((((c4 + 0) >> 3) & 7) << 2)] = kv.x;
            ksT[c4 + 1][j ^ ((((c4 + 1) >> 3) & 7) << 2)] = kv.y;
            ksT[c4 + 2][j ^ ((((c4 + 2) >> 3) & 7) << 2)] = kv.z;
            ksT[c4 + 3][j ^ ((((c4 + 3) >> 3) & 7) << 2)] = kv.w;
            *(float4*)&vsm[j][c4] = vv;
        }
        __syncthreads();

        // QK^T: this thread's row r vs its 16 keys [cu, cu+16)
        float s[16];
        #pragma unroll
        for (int i = 0; i < 16; ++i) s[i] = 0.f;
        #pragma unroll 4
        for (int d = 0; d < 64; ++d) {
            const int sw = ((d >> 3) & 7) << 2;
            const float q0 = qsT[d][r ^ sw];
            #pragma unroll
            for (int j4 = 0; j4 < 4; ++j4) {
                const float4 k4 = *(const float4*)&ksT[d][(cu + (j4 << 2)) ^ sw];
                s[j4 * 4 + 0] += q0 * k4.x;
                s[j4 * 4 + 1] += q0 * k4.y;
                s[j4 * 4 + 2] += q0 * k4.z;
                s[j4 * 4 + 3] += q0 * k4.w;
            }
        }
        if (kbase + 64 > N_TOK) {       // mask padded keys
            #pragma unroll
            for (int jj = 0; jj < 16; ++jj)
                if (kbase + cu + jj >= N_TOK) s[jj] = -1e30f;
        }

        // online softmax (row reduce across 4 slice-lanes)
        float tm = s[0];
        #pragma unroll
        for (int jj = 1; jj < 16; ++jj) tm = fmaxf(tm, s[jj]);
        tm = fmaxf(tm, __shfl_xor(tm, 1));
        tm = fmaxf(tm, __shfl_xor(tm, 2));
        const float mn = fmaxf(m0, tm);
        const float al = __expf(m0 - mn);
        float ts = 0.f;
        #pragma unroll
        for (int jj = 0; jj < 16; ++jj) { s[jj] = __expf(s[jj] - mn); ts += s[jj]; }
        l0 = l0 * al + ts;
        m0 = mn;
        #pragma unroll
        for (int i = 0; i < 16; ++i) acc[i] *= al;

        // PV: p broadcast across the 4 slice lanes of this row via shfl
        #pragma unroll
        for (int jj = 0; jj < 16; ++jj) {
            for (int us = 0; us < 4; ++us) {
                const int j = (us << 4) + jj;
                const float p = __shfl(s[jj], (tid & 60) | us);
                #pragma unroll
                for (int j4 = 0; j4 < 4; ++j4) {
                    const float4 v4 = *(const float4*)&vsm[j][cu + (j4 << 2)];
                    acc[j4 * 4 + 0] += p * v4.x;
                    acc[j4 * 4 + 1] += p * v4.y;
                    acc[j4 * 4 + 2] += p * v4.z;
                    acc[j4 * 4 + 3] += p * v4.w;
                }
            }
        }
    }

    l0 += __shfl_xor(l0, 1);
    l0 += __shfl_xor(l0, 2);
    const float inv = 1.f / l0;
    const int gr = qb * 64 + r;
    if (gr < N_TOK) {
        float* dst = Ob + (size_t)gr * CDIM + h * HD + cu;
        #pragma unroll
        for (int j4 = 0; j4 < 4; ++j4)
            *(float4*)(dst + (j4 << 2)) = make_float4(acc[j4 * 4 + 0] * inv, acc[j4 * 4 + 1] * inv,
                                                      acc[j4 * 4 + 2] * inv, acc[j4 * 4 + 3] * inv);
    }
}

// ---------------- Kernel 3: output projection GEMM ----------------
__global__ __launch_bounds__(256)
void proj_gemm(const float* __restrict__ Ain, const float* __restrict__ Wp,
               const float* __restrict__ bp, float* __restrict__ out)
{
    __shared__ __align__(16) float As[16][64];
    __shared__ __align__(16) float Bs[16][64];

    const int rb = blockIdx.x;
    const int colbase = blockIdx.y * 64;
    const int tid = threadIdx.x;
    const int tx = tid & 15, ty = tid >> 4;

    const int ar = tid >> 2;
    const int ak4 = (tid & 3) << 2;
    int agr = rb * 64 + ar;
    if (agr >= N_TOK) agr = N_TOK - 1;
    const int bk = tid >> 4;
    const int bc4 = (tid & 15) << 2;

    float acc[4][4];
    #pragma unroll
    for (int i = 0; i < 4; ++i) {
        #pragma unroll
        for (int j = 0; j < 4; ++j) acc[i][j] = 0.f;
    }

    for (int k0 = 0; k0 < CDIM; k0 += 16) {
        const float4 a4 = *(const float4*)(Ain + (size_t)agr * CDIM + k0 + ak4);
        const float4 b4 = *(const float4*)(Wp + (size_t)(k0 + bk) * CDIM + colbase + bc4);
        __syncthreads();
        As[ak4 + 0][ar] = a4.x;
        As[ak4 + 1][ar] = a4.y;
        As[ak4 + 2][ar] = a4.z;
        As[ak4 + 3][ar] = a4.w;
        *(float4*)&Bs[bk][bc4] = b4;
        __syncthreads();
        #pragma unroll
        for (int kk = 0; kk < 16; ++kk) {
            const float4 av = *(const float4*)&As[kk][ty << 2];
            const float4 bv = *(const float4*)&Bs[kk][tx << 2];
            acc[0][0] += av.x * bv.x; acc[0][1] += av.x * bv.y; acc[0][2] += av.x * bv.z; acc[0][3] += av.x * bv.w;
            acc[1][0] += av.y * bv.x; acc[1][1] += av.y * bv.y; acc[1][2] += av.y * bv.z; acc[1][3] += av.y * bv.w;
            acc[2][0] += av.z * bv.x; acc[2][1] += av.z * bv.y; acc[2][2] += av.z * bv.z; acc[2][3] += av.z * bv.w;
            acc[3][0] += av.w * bv.x; acc[3][1] += av.w * bv.y; acc[3][2] += av.w * bv.z; acc[3][3] += av.w * bv.w;
        }
    }

    #pragma unroll
    for (int i = 0; i < 4; ++i) {
        const int gr = rb * 64 + (ty << 2) + i;
        if (gr < N_TOK) {
            float4 o;
            o.x = acc[i][0] + bp[colbase + (tx << 2) + 0];
            o.y = acc[i][1] + bp[colbase + (tx << 2) + 1];
            o.z = acc[i][2] + bp[colbase + (tx << 2) + 2];
            o.w = acc[i][3] + bp[colbase + (tx << 2) + 3];
            *(float4*)(out + (size_t)gr * CDIM + colbase + (tx << 2)) = o;
        }
    }
}

extern "C" void kernel_launch(void* const* d_in, const int* in_sizes, int n_in,
                              void* d_out, int out_size, void* d_ws, size_t ws_size,
                              hipStream_t stream)
{
    const float* q_tokens = (const float*)d_in[0];
    const float* t_tokens = (const float*)d_in[1];
    const float* pos2d    = (const float*)d_in[2];
    const float* tposes   = (const float*)d_in[3];
    const float* Wqkv     = (const float*)d_in[4];
    const float* bqkv     = (const float*)d_in[5];
    const float* Wproj    = (const float*)d_in[6];
    const float* bproj    = (const float*)d_in[7];
    float* out = (float*)d_out;

    const size_t hbuf = (size_t)NH * N_TOK * HD;   // per Q/K/V buffer (floats)
    float* Qb = (float*)d_ws;
    float* Kb = Qb + hbuf;
    float* Vb = Kb + hbuf;
    float* Ob = Vb + hbuf;                          // N x 768

    dim3 g1((N_TOK + 63) / 64, 36);
    qkv_rope_so3<<<g1, 256, 0, stream>>>(q_tokens, t_tokens, pos2d, tposes, Wqkv, bqkv, Qb, Kb, Vb);

    dim3 g2((N_TOK + 63) / 64, NH);
    attn_fp32<<<g2, 256, 0, stream>>>(Qb, Kb, Vb, Ob);

    dim3 g3((N_TOK + 63) / 64, CDIM / 64);
    proj_gemm<<<g3, 256, 0, stream>>>(Ob, Wproj, bproj, out);
}

// Round 2
// 449.079 us; speedup vs baseline: 2.1133x; 2.1133x over previous
//
#include <hip/hip_runtime.h>
#include <math.h>

#define N_TOK 2884
#define HW_IMG 576
#define NT_TOK 577
#define CDIM 768
#define NH 12
#define HD 64
#define QKV_COLS 2304

typedef float f32x4 __attribute__((ext_vector_type(4)));
typedef short bf16x8 __attribute__((ext_vector_type(8)));
typedef unsigned int u32x4 __attribute__((ext_vector_type(4)));

static __device__ __forceinline__ unsigned short f2bf(float f) {
    unsigned u = __float_as_uint(f);
    return (unsigned short)((u + 0x7fffu + ((u >> 16) & 1u)) >> 16);
}
static __device__ __forceinline__ float bf2f(unsigned short h) {
    return __uint_as_float(((unsigned)h) << 16);
}

// ---------------- Kernel 1: QKV GEMM + bias + RoPE2D + SO3 epilogue (fp32) ----------------
__global__ __launch_bounds__(256)
void qkv_rope_so3(const float* __restrict__ q_tokens,
                  const float* __restrict__ t_tokens,
                  const float* __restrict__ pos2d,
                  const float* __restrict__ tposes,
                  const float* __restrict__ Wqkv,
                  const float* __restrict__ bqkv,
                  float* __restrict__ Qb,
                  float* __restrict__ Kb,
                  float* __restrict__ Vb)
{
    __shared__ __align__(16) float As[16][64];
    __shared__ __align__(16) float Bs[16][64];
    __shared__ float Ct[64][65];

    const int rb = blockIdx.x;
    const int cb = blockIdx.y;
    const int which = cb / NH;
    const int h = cb - which * NH;
    const int colbase = cb * 64;
    const int tid = threadIdx.x;
    const int tx = tid & 15, ty = tid >> 4;

    const int ar = tid >> 2;
    const int ak4 = (tid & 3) << 2;
    int agr = rb * 64 + ar;
    if (agr >= N_TOK) agr = N_TOK - 1;
    const float* arow = (agr < HW_IMG) ? (q_tokens + (size_t)agr * CDIM)
                                       : (t_tokens + (size_t)(agr - HW_IMG) * CDIM);
    const int bk = tid >> 4;
    const int bc4 = (tid & 15) << 2;

    float acc[4][4];
    #pragma unroll
    for (int i = 0; i < 4; ++i)
        #pragma unroll
        for (int j = 0; j < 4; ++j) acc[i][j] = 0.f;

    for (int k0 = 0; k0 < CDIM; k0 += 16) {
        const float4 a4 = *(const float4*)(arow + k0 + ak4);
        const float4 b4 = *(const float4*)(Wqkv + (size_t)(k0 + bk) * QKV_COLS + colbase + bc4);
        __syncthreads();
        As[ak4 + 0][ar] = a4.x;
        As[ak4 + 1][ar] = a4.y;
        As[ak4 + 2][ar] = a4.z;
        As[ak4 + 3][ar] = a4.w;
        *(float4*)&Bs[bk][bc4] = b4;
        __syncthreads();
        #pragma unroll
        for (int kk = 0; kk < 16; ++kk) {
            const float4 av = *(const float4*)&As[kk][ty << 2];
            const float4 bv = *(const float4*)&Bs[kk][tx << 2];
            acc[0][0] += av.x * bv.x; acc[0][1] += av.x * bv.y; acc[0][2] += av.x * bv.z; acc[0][3] += av.x * bv.w;
            acc[1][0] += av.y * bv.x; acc[1][1] += av.y * bv.y; acc[1][2] += av.y * bv.z; acc[1][3] += av.y * bv.w;
            acc[2][0] += av.z * bv.x; acc[2][1] += av.z * bv.y; acc[2][2] += av.z * bv.z; acc[2][3] += av.z * bv.w;
            acc[3][0] += av.w * bv.x; acc[3][1] += av.w * bv.y; acc[3][2] += av.w * bv.z; acc[3][3] += av.w * bv.w;
        }
    }

    #pragma unroll
    for (int i = 0; i < 4; ++i)
        #pragma unroll
        for (int j = 0; j < 4; ++j)
            Ct[(ty << 2) + i][(tx << 2) + j] = acc[i][j] + bqkv[colbase + (tx << 2) + j];
    __syncthreads();

    const int er = tid >> 2;
    const int eu = tid & 3;
    const int n = rb * 64 + er;
    if (n < N_TOK) {
        float outv[16];
        const bool is_img = (n < HW_IMG);
        int ts = 0, tj = 0;
        if (!is_img) { const int m = n - HW_IMG; ts = m / NT_TOK; tj = m - ts * NT_TOK; }

        if (which < 2 && is_img) {
            const float p = (eu < 2) ? pos2d[2 * n] : pos2d[2 * n + 1];
            const bool lowhalf = ((eu & 1) == 0);
            #pragma unroll
            for (int dd = 0; dd < 16; ++dd) {
                const int d = (eu << 4) + dd;
                float sv, cv;
                sincosf(p * expf((float)dd * -0.28782313662425574f), &sv, &cv);
                const float rot = lowhalf ? -Ct[er][d + 16] : Ct[er][d - 16];
                outv[dd] = Ct[er][d] * cv + rot * sv;
            }
        } else if (which < 2 && !is_img && tj < HW_IMG) {
            #pragma unroll
            for (int dd = 0; dd < 16; ++dd) {
                const int d = (eu << 4) + dd;
                float val = Ct[er][d];
                if (d < 30) {
                    const int g = d / 3;
                    const float* R = tposes + ts * 16 + (d - g * 3) * 4;
                    val = R[0] * Ct[er][g * 3] + R[1] * Ct[er][g * 3 + 1] + R[2] * Ct[er][g * 3 + 2];
                }
                outv[dd] = val;
            }
        } else {
            #pragma unroll
            for (int dd = 0; dd < 16; ++dd) outv[dd] = Ct[er][(eu << 4) + dd];
        }

        float* dst = (which == 0 ? Qb : which == 1 ? Kb : Vb)
                   + ((size_t)h * N_TOK + n) * HD + (eu << 4);
        #pragma unroll
        for (int q4 = 0; q4 < 4; ++q4)
            *(float4*)(dst + (q4 << 2)) = make_float4(outv[q4 * 4 + 0], outv[q4 * 4 + 1],
                                                      outv[q4 * 4 + 2], outv[q4 * 4 + 3]);
    }
}

// ---------------- Kernel 2: MFMA bf16 hi/lo flash attention ----------------
// grid (46 q-tiles, 12 heads), 256 threads = 4 waves, wave w owns q-rows w*16..w*16+15
__global__ __launch_bounds__(256)
void attn_mfma(const float* __restrict__ Qb, const float* __restrict__ Kb,
               const float* __restrict__ Vb, float* __restrict__ Ob)
{
    // K: [key][dim] bf16 hi/lo; Vt: [dim][key] bf16 hi/lo; P2: [row][key] packed (hi | lo<<16)
    __shared__ __align__(16) unsigned short Khi[64][64];
    __shared__ __align__(16) unsigned short Klo[64][64];
    __shared__ __align__(16) unsigned short Vthi[64][64];
    __shared__ __align__(16) unsigned short Vtlo[64][64];
    __shared__ __align__(16) unsigned int   P2[64][64];

    const int h  = blockIdx.y;
    const int qb = blockIdx.x;
    const int tid = threadIdx.x;
    const int w  = tid >> 6;      // wave id
    const int l  = tid & 63;
    const int lr = l & 15;        // lane row/col index
    const int lg = l >> 4;        // lane group 0..3

    const float* Qh = Qb + (size_t)h * N_TOK * HD;
    const float* Kh = Kb + (size_t)h * N_TOK * HD;
    const float* Vh = Vb + (size_t)h * N_TOK * HD;

    // ---- preload Q A-fragments (this wave's 16 rows), scaled by 1/8, split hi/lo ----
    bf16x8 qh_[2], ql_[2];
    {
        int row = qb * 64 + w * 16 + lr;
        if (row >= N_TOK) row = N_TOK - 1;
        const float* qp = Qh + (size_t)row * HD + lg * 8;
        #pragma unroll
        for (int ks = 0; ks < 2; ++ks) {
            const float4 a = *(const float4*)(qp + ks * 32);
            const float4 b = *(const float4*)(qp + ks * 32 + 4);
            float fv[8] = {a.x, a.y, a.z, a.w, b.x, b.y, b.z, b.w};
            #pragma unroll
            for (int e = 0; e < 8; ++e) {
                const float f = fv[e] * 0.125f;
                const unsigned short hs = f2bf(f);
                qh_[ks][e] = (short)hs;
                ql_[ks][e] = (short)f2bf(f - bf2f(hs));
            }
        }
    }

    float m0[4] = {-1e30f, -1e30f, -1e30f, -1e30f};
    float l0[4] = {0.f, 0.f, 0.f, 0.f};
    f32x4 acc[4];
    #pragma unroll
    for (int db = 0; db < 4; ++db) acc[db] = (f32x4){0.f, 0.f, 0.f, 0.f};

    // staging maps
    const int skey = tid >> 2;            // K stage: key per thread
    const int sdc  = (tid & 3) << 4;      // 16-dim chunk
    const int vk   = (tid & 15) << 2;     // V stage: 4 keys
    const int vd   = (tid >> 4) << 2;     // 4 dims

    const int NTILE = (N_TOK + 63) / 64;  // 46
    for (int kt = 0; kt < NTILE; ++kt) {
        const int kbase = kt << 6;
        __syncthreads();   // prev tile fully consumed

        // ---- stage K tile: [key][dim] hi/lo ----
        {
            int gk = kbase + skey;
            if (gk >= N_TOK) gk = N_TOK - 1;
            const float* kp = Kh + (size_t)gk * HD + sdc;
            float kv[16];
            #pragma unroll
            for (int c = 0; c < 4; ++c) {
                const float4 f = *(const float4*)(kp + c * 4);
                kv[c * 4 + 0] = f.x; kv[c * 4 + 1] = f.y; kv[c * 4 + 2] = f.z; kv[c * 4 + 3] = f.w;
            }
            unsigned short hs[16], ls[16];
            #pragma unroll
            for (int e = 0; e < 16; ++e) {
                hs[e] = f2bf(kv[e]);
                ls[e] = f2bf(kv[e] - bf2f(hs[e]));
            }
            const int sw = (skey & 7) << 3;
            bf16x8 h0, h1, l0v, l1v;
            #pragma unroll
            for (int e = 0; e < 8; ++e) {
                h0[e] = (short)hs[e];   h1[e] = (short)hs[8 + e];
                l0v[e] = (short)ls[e];  l1v[e] = (short)ls[8 + e];
            }
            *(bf16x8*)&Khi[skey][(sdc + 0) ^ sw] = h0;
            *(bf16x8*)&Khi[skey][(sdc + 8) ^ sw] = h1;
            *(bf16x8*)&Klo[skey][(sdc + 0) ^ sw] = l0v;
            *(bf16x8*)&Klo[skey][(sdc + 8) ^ sw] = l1v;
        }
        // ---- stage V tile transposed: [dim][key] hi/lo (4x4 register transpose) ----
        {
            float va[4][4];
            #pragma unroll
            for (int i = 0; i < 4; ++i) {
                int gk = kbase + vk + i;
                if (gk >= N_TOK) gk = N_TOK - 1;
                const float4 f = *(const float4*)(Vh + (size_t)gk * HD + vd);
                va[i][0] = f.x; va[i][1] = f.y; va[i][2] = f.z; va[i][3] = f.w;
            }
            #pragma unroll
            for (int j = 0; j < 4; ++j) {
                const int dd = vd + j;
                const int sw = (dd & 7) << 3;
                ushort4 wh, wl;
                unsigned short t;
                t = f2bf(va[0][j]); wh.x = t; wl.x = f2bf(va[0][j] - bf2f(t));
                t = f2bf(va[1][j]); wh.y = t; wl.y = f2bf(va[1][j] - bf2f(t));
                t = f2bf(va[2][j]); wh.z = t; wl.z = f2bf(va[2][j] - bf2f(t));
                t = f2bf(va[3][j]); wh.w = t; wl.w = f2bf(va[3][j] - bf2f(t));
                *(ushort4*)&Vthi[dd][vk ^ sw] = wh;
                *(ushort4*)&Vtlo[dd][vk ^ sw] = wl;
            }
        }
        __syncthreads();

        // ---- S = Q K^T via MFMA (hi*hi + hi*lo + lo*hi) ----
        f32x4 s[4];
        #pragma unroll
        for (int kb = 0; kb < 4; ++kb) {
            s[kb] = (f32x4){0.f, 0.f, 0.f, 0.f};
            const int key = kb * 16 + lr;
            const int sw = (key & 7) << 3;
            #pragma unroll
            for (int ks = 0; ks < 2; ++ks) {
                const bf16x8 bh = *(const bf16x8*)&Khi[key][(ks * 32 + lg * 8) ^ sw];
                const bf16x8 bl = *(const bf16x8*)&Klo[key][(ks * 32 + lg * 8) ^ sw];
                s[kb] = __builtin_amdgcn_mfma_f32_16x16x32_bf16(qh_[ks], bh, s[kb], 0, 0, 0);
                s[kb] = __builtin_amdgcn_mfma_f32_16x16x32_bf16(qh_[ks], bl, s[kb], 0, 0, 0);
                s[kb] = __builtin_amdgcn_mfma_f32_16x16x32_bf16(ql_[ks], bh, s[kb], 0, 0, 0);
            }
        }

        // mask padded keys (last tile only)
        if (kbase + 64 > N_TOK) {
            #pragma unroll
            for (int kb = 0; kb < 4; ++kb)
                if (kbase + kb * 16 + lr >= N_TOK) {
                    #pragma unroll
                    for (int r = 0; r < 4; ++r) s[kb][r] = -1e30f;
                }
        }

        // ---- online softmax in C-fragment registers ----
        float mt[4], al[4];
        #pragma unroll
        for (int r = 0; r < 4; ++r)
            mt[r] = fmaxf(fmaxf(s[0][r], s[1][r]), fmaxf(s[2][r], s[3][r]));
        #pragma unroll
        for (int r = 0; r < 4; ++r) {
            mt[r] = fmaxf(mt[r], __shfl_xor(mt[r], 1));
            mt[r] = fmaxf(mt[r], __shfl_xor(mt[r], 2));
            mt[r] = fmaxf(mt[r], __shfl_xor(mt[r], 4));
            mt[r] = fmaxf(mt[r], __shfl_xor(mt[r], 8));
        }
        #pragma unroll
        for (int r = 0; r < 4; ++r) {
            const float mn = fmaxf(m0[r], mt[r]);
            al[r] = __expf(m0[r] - mn);
            m0[r] = mn;
        }
        #pragma unroll
        for (int kb = 0; kb < 4; ++kb)
            #pragma unroll
            for (int r = 0; r < 4; ++r)
                s[kb][r] = __expf(s[kb][r] - m0[r]);
        #pragma unroll
        for (int r = 0; r < 4; ++r)
            l0[r] = l0[r] * al[r] + (s[0][r] + s[1][r] + s[2][r] + s[3][r]);  // per-lane partial sum
        #pragma unroll
        for (int db = 0; db < 4; ++db)
            #pragma unroll
            for (int r = 0; r < 4; ++r) acc[db][r] *= al[r];

        // ---- pack P hi/lo and write to LDS [row][key] ----
        #pragma unroll
        for (int r = 0; r < 4; ++r) {
            const int rw = w * 16 + lg * 4 + r;
            const int swp = (rw & 7) << 2;
            #pragma unroll
            for (int kb = 0; kb < 4; ++kb) {
                const float p = s[kb][r];
                const unsigned short ph = f2bf(p);
                const unsigned short pl = f2bf(p - bf2f(ph));
                P2[rw][(kb * 16 + lr) ^ swp] = (unsigned)ph | ((unsigned)pl << 16);
            }
        }
        __syncthreads();

        // ---- PV via MFMA: acc += P * V ----
        const int arow = w * 16 + lr;
        const int swa = (arow & 7) << 2;
        #pragma unroll
        for (int ks = 0; ks < 2; ++ks) {
            const int kb8 = ks * 32 + lg * 8;
            const u32x4 pa = *(const u32x4*)&P2[arow][(kb8 + 0) ^ swa];
            const u32x4 pb = *(const u32x4*)&P2[arow][(kb8 + 4) ^ swa];
            bf16x8 ph, pl;
            #pragma unroll
            for (int e = 0; e < 4; ++e) {
                ph[e]     = (short)(pa[e] & 0xffffu);
                pl[e]     = (short)(pa[e] >> 16);
                ph[4 + e] = (short)(pb[e] & 0xffffu);
                pl[4 + e] = (short)(pb[e] >> 16);
            }
            #pragma unroll
            for (int db = 0; db < 4; ++db) {
                const int vr = db * 16 + lr;
                const int swv = (vr & 7) << 3;
                const bf16x8 vh = *(const bf16x8*)&Vthi[vr][kb8 ^ swv];
                const bf16x8 vl = *(const bf16x8*)&Vtlo[vr][kb8 ^ swv];
                acc[db] = __builtin_amdgcn_mfma_f32_16x16x32_bf16(ph, vh, acc[db], 0, 0, 0);
                acc[db] = __builtin_amdgcn_mfma_f32_16x16x32_bf16(ph, vl, acc[db], 0, 0, 0);
                acc[db] = __builtin_amdgcn_mfma_f32_16x16x32_bf16(pl, vh, acc[db], 0, 0, 0);
            }
        }
    }

    // ---- epilogue: reduce row sums across the 16-lane row group, normalize, write ----
    #pragma unroll
    for (int r = 0; r < 4; ++r) {
        l0[r] += __shfl_xor(l0[r], 1);
        l0[r] += __shfl_xor(l0[r], 2);
        l0[r] += __shfl_xor(l0[r], 4);
        l0[r] += __shfl_xor(l0[r], 8);
    }
    const int orow0 = qb * 64 + w * 16 + lg * 4;
    #pragma unroll
    for (int r = 0; r < 4; ++r) {
        const int row = orow0 + r;
        if (row < N_TOK) {
            const float inv = 1.0f / l0[r];
            #pragma unroll
            for (int db = 0; db < 4; ++db)
                Ob[(size_t)row * CDIM + h * HD + db * 16 + lr] = acc[db][r] * inv;
        }
    }
}

// ---------------- Kernel 3: output projection GEMM (fp32) ----------------
__global__ __launch_bounds__(256)
void proj_gemm(const float* __restrict__ Ain, const float* __restrict__ Wp,
               const float* __restrict__ bp, float* __restrict__ out)
{
    __shared__ __align__(16) float As[16][64];
    __shared__ __align__(16) float Bs[16][64];

    const int rb = blockIdx.x;
    const int colbase = blockIdx.y * 64;
    const int tid = threadIdx.x;
    const int tx = tid & 15, ty = tid >> 4;

    const int ar = tid >> 2;
    const int ak4 = (tid & 3) << 2;
    int agr = rb * 64 + ar;
    if (agr >= N_TOK) agr = N_TOK - 1;
    const int bk = tid >> 4;
    const int bc4 = (tid & 15) << 2;

    float acc[4][4];
    #pragma unroll
    for (int i = 0; i < 4; ++i)
        #pragma unroll
        for (int j = 0; j < 4; ++j) acc[i][j] = 0.f;

    for (int k0 = 0; k0 < CDIM; k0 += 16) {
        const float4 a4 = *(const float4*)(Ain + (size_t)agr * CDIM + k0 + ak4);
        const float4 b4 = *(const float4*)(Wp + (size_t)(k0 + bk) * CDIM + colbase + bc4);
        __syncthreads();
        As[ak4 + 0][ar] = a4.x;
        As[ak4 + 1][ar] = a4.y;
        As[ak4 + 2][ar] = a4.z;
        As[ak4 + 3][ar] = a4.w;
        *(float4*)&Bs[bk][bc4] = b4;
        __syncthreads();
        #pragma unroll
        for (int kk = 0; kk < 16; ++kk) {
            const float4 av = *(const float4*)&As[kk][ty << 2];
            const float4 bv = *(const float4*)&Bs[kk][tx << 2];
            acc[0][0] += av.x * bv.x; acc[0][1] += av.x * bv.y; acc[0][2] += av.x * bv.z; acc[0][3] += av.x * bv.w;
            acc[1][0] += av.y * bv.x; acc[1][1] += av.y * bv.y; acc[1][2] += av.y * bv.z; acc[1][3] += av.y * bv.w;
            acc[2][0] += av.z * bv.x; acc[2][1] += av.z * bv.y; acc[2][2] += av.z * bv.z; acc[2][3] += av.z * bv.w;
            acc[3][0] += av.w * bv.x; acc[3][1] += av.w * bv.y; acc[3][2] += av.w * bv.z; acc[3][3] += av.w * bv.w;
        }
    }

    #pragma unroll
    for (int i = 0; i < 4; ++i) {
        const int gr = rb * 64 + (ty << 2) + i;
        if (gr < N_TOK) {
            float4 o;
            o.x = acc[i][0] + bp[colbase + (tx << 2) + 0];
            o.y = acc[i][1] + bp[colbase + (tx << 2) + 1];
            o.z = acc[i][2] + bp[colbase + (tx << 2) + 2];
            o.w = acc[i][3] + bp[colbase + (tx << 2) + 3];
            *(float4*)(out + (size_t)gr * CDIM + colbase + (tx << 2)) = o;
        }
    }
}

extern "C" void kernel_launch(void* const* d_in, const int* in_sizes, int n_in,
                              void* d_out, int out_size, void* d_ws, size_t ws_size,
                              hipStream_t stream)
{
    const float* q_tokens = (const float*)d_in[0];
    const float* t_tokens = (const float*)d_in[1];
    const float* pos2d    = (const float*)d_in[2];
    const float* tposes   = (const float*)d_in[3];
    const float* Wqkv     = (const float*)d_in[4];
    const float* bqkv     = (const float*)d_in[5];
    const float* Wproj    = (const float*)d_in[6];
    const float* bproj    = (const float*)d_in[7];
    float* out = (float*)d_out;

    const size_t hbuf = (size_t)NH * N_TOK * HD;
    float* Qb = (float*)d_ws;
    float* Kb = Qb + hbuf;
    float* Vb = Kb + hbuf;
    float* Ob = Vb + hbuf;

    dim3 g1((N_TOK + 63) / 64, 36);
    qkv_rope_so3<<<g1, 256, 0, stream>>>(q_tokens, t_tokens, pos2d, tposes, Wqkv, bqkv, Qb, Kb, Vb);

    dim3 g2((N_TOK + 63) / 64, NH);
    attn_mfma<<<g2, 256, 0, stream>>>(Qb, Kb, Vb, Ob);

    dim3 g3((N_TOK + 63) / 64, CDIM / 64);
    proj_gemm<<<g3, 256, 0, stream>>>(Ob, Wproj, bproj, out);
}

// Round 4
// 306.652 us; speedup vs baseline: 3.0948x; 1.4645x over previous
//
#include <hip/hip_runtime.h>
#include <math.h>

#define N_TOK 2884
#define HW_IMG 576
#define NT_TOK 577
#define CDIM 768
#define NH 12
#define HD 64
#define QKV_COLS 2304
#define NVP 2888   // padded token stride for V^T planes (multiple of 8)

typedef float f32x4 __attribute__((ext_vector_type(4)));
typedef short bf16x8 __attribute__((ext_vector_type(8)));
typedef unsigned short u16;
typedef unsigned short u16x8 __attribute__((ext_vector_type(8)));
typedef unsigned short u16x4 __attribute__((ext_vector_type(4)));
typedef unsigned int u32x4 __attribute__((ext_vector_type(4)));

static __device__ __forceinline__ u16 f2bf(float f) {
    unsigned u = __float_as_uint(f);
    return (u16)((u + 0x7fffu + ((u >> 16) & 1u)) >> 16);
}
static __device__ __forceinline__ float bf2f(u16 h) {
    return __uint_as_float(((unsigned)h) << 16);
}
static __device__ __forceinline__ void split1(float f, u16& h, u16& l) {
    h = f2bf(f);
    l = f2bf(f - bf2f(h));
}

// ---------------- conv_x: concat(q_tokens, t_tokens) -> hi/lo planes ----------------
__global__ __launch_bounds__(256)
void conv_x(const float* __restrict__ q, const float* __restrict__ t,
            u16* __restrict__ Xhi, u16* __restrict__ Xlo)
{
    const int i = (blockIdx.x * 256 + threadIdx.x) * 4;
    const int SPLIT = HW_IMG * CDIM;
    const float4 v = (i < SPLIT) ? *(const float4*)(q + i) : *(const float4*)(t + (i - SPLIT));
    u16x4 h, l;
    u16 hh, ll;
    split1(v.x, hh, ll); h[0] = hh; l[0] = ll;
    split1(v.y, hh, ll); h[1] = hh; l[1] = ll;
    split1(v.z, hh, ll); h[2] = hh; l[2] = ll;
    split1(v.w, hh, ll); h[3] = hh; l[3] = ll;
    *(u16x4*)(Xhi + i) = h;
    *(u16x4*)(Xlo + i) = l;
}

// ---------------- conv_wT: W[k][n] fp32 -> transposed hi/lo planes [n][k=768] ----------------
__global__ __launch_bounds__(256)
void conv_wT(const float* __restrict__ W, int ncols,
             u16* __restrict__ Thi, u16* __restrict__ Tlo)
{
    __shared__ float T[64][65];
    const int k0 = blockIdx.x * 64;
    const int n0 = blockIdx.y * 64;
    const int tid = threadIdx.x;
    {
        const int kr = tid >> 2, nch = (tid & 3) << 4;
        const float* src = W + (size_t)(k0 + kr) * ncols + n0 + nch;
        #pragma unroll
        for (int c = 0; c < 4; ++c) {
            const float4 f = *(const float4*)(src + c * 4);
            T[kr][nch + c * 4 + 0] = f.x;
            T[kr][nch + c * 4 + 1] = f.y;
            T[kr][nch + c * 4 + 2] = f.z;
            T[kr][nch + c * 4 + 3] = f.w;
        }
    }
    __syncthreads();
    const int nr = tid >> 2, kch = (tid & 3) << 4;
    u16x8 h0, h1, l0v, l1v;
    #pragma unroll
    for (int j = 0; j < 8; ++j) { u16 hh, ll; split1(T[kch + j][nr], hh, ll); h0[j] = hh; l0v[j] = ll; }
    #pragma unroll
    for (int j = 0; j < 8; ++j) { u16 hh, ll; split1(T[kch + 8 + j][nr], hh, ll); h1[j] = hh; l1v[j] = ll; }
    const size_t dst = (size_t)(n0 + nr) * CDIM + k0 + kch;
    *(u16x8*)(Thi + dst) = h0;     *(u16x8*)(Thi + dst + 8) = h1;
    *(u16x8*)(Tlo + dst) = l0v;    *(u16x8*)(Tlo + dst + 8) = l1v;
}

// ---------------- Kernel 1: QKV via MFMA hi/lo + bias + RoPE2D + SO3, writes planes ----------------
__global__ __launch_bounds__(256)
void qkv_mfma(const u16* __restrict__ Xhi, const u16* __restrict__ Xlo,
              const u16* __restrict__ Whi, const u16* __restrict__ Wlo,
              const float* __restrict__ bqkv,
              const float* __restrict__ pos2d, const float* __restrict__ tposes,
              u16* __restrict__ Qhi, u16* __restrict__ Qlo,
              u16* __restrict__ Khi, u16* __restrict__ Klo,
              u16* __restrict__ Vthi, u16* __restrict__ Vtlo)
{
    __shared__ __align__(16) u16 Ah[64][64], Al[64][64], Bh[64][64], Bl[64][64];
    __shared__ float Ct[64][65];

    const int rb = blockIdx.x;
    const int cb = blockIdx.y;
    const int which = cb / NH;
    const int h = cb - which * NH;
    const int colbase = cb * 64;
    const int tid = threadIdx.x;
    const int w = tid >> 6, l = tid & 63;
    const int lr = l & 15, lg = l >> 4;

    const int srow = tid >> 2, sch = (tid & 3) << 4;
    int arow = rb * 64 + srow;
    if (arow >= N_TOK) arow = N_TOK - 1;
    const size_t abase = (size_t)arow * CDIM + sch;
    const size_t bbase = (size_t)(colbase + srow) * CDIM + sch;

    f32x4 acc[4];
    #pragma unroll
    for (int i = 0; i < 4; ++i) acc[i] = (f32x4){0.f, 0.f, 0.f, 0.f};

    const int sw = (srow & 7) << 3;
    const int swf = (lr & 7) << 3;

    for (int k0 = 0; k0 < CDIM; k0 += 64) {
        const u16x8 a0h = *(const u16x8*)(Xhi + abase + k0);
        const u16x8 a1h = *(const u16x8*)(Xhi + abase + k0 + 8);
        const u16x8 a0l = *(const u16x8*)(Xlo + abase + k0);
        const u16x8 a1l = *(const u16x8*)(Xlo + abase + k0 + 8);
        const u16x8 b0h = *(const u16x8*)(Whi + bbase + k0);
        const u16x8 b1h = *(const u16x8*)(Whi + bbase + k0 + 8);
        const u16x8 b0l = *(const u16x8*)(Wlo + bbase + k0);
        const u16x8 b1l = *(const u16x8*)(Wlo + bbase + k0 + 8);
        __syncthreads();
        *(u16x8*)&Ah[srow][(sch + 0) ^ sw] = a0h;
        *(u16x8*)&Ah[srow][(sch + 8) ^ sw] = a1h;
        *(u16x8*)&Al[srow][(sch + 0) ^ sw] = a0l;
        *(u16x8*)&Al[srow][(sch + 8) ^ sw] = a1l;
        *(u16x8*)&Bh[srow][(sch + 0) ^ sw] = b0h;
        *(u16x8*)&Bh[srow][(sch + 8) ^ sw] = b1h;
        *(u16x8*)&Bl[srow][(sch + 0) ^ sw] = b0l;
        *(u16x8*)&Bl[srow][(sch + 8) ^ sw] = b1l;
        __syncthreads();
        #pragma unroll
        for (int ks = 0; ks < 2; ++ks) {
            const int koff = (ks * 32 + lg * 8) ^ swf;
            const bf16x8 ah_ = *(const bf16x8*)&Ah[w * 16 + lr][koff];
            const bf16x8 al_ = *(const bf16x8*)&Al[w * 16 + lr][koff];
            #pragma unroll
            for (int cbk = 0; cbk < 4; ++cbk) {
                const bf16x8 bh_ = *(const bf16x8*)&Bh[cbk * 16 + lr][koff];
                const bf16x8 bl_ = *(const bf16x8*)&Bl[cbk * 16 + lr][koff];
                acc[cbk] = __builtin_amdgcn_mfma_f32_16x16x32_bf16(ah_, bh_, acc[cbk], 0, 0, 0);
                acc[cbk] = __builtin_amdgcn_mfma_f32_16x16x32_bf16(ah_, bl_, acc[cbk], 0, 0, 0);
                acc[cbk] = __builtin_amdgcn_mfma_f32_16x16x32_bf16(al_, bh_, acc[cbk], 0, 0, 0);
            }
        }
    }

    #pragma unroll
    for (int cbk = 0; cbk < 4; ++cbk)
        #pragma unroll
        for (int r = 0; r < 4; ++r)
            Ct[w * 16 + lg * 4 + r][cbk * 16 + lr] = acc[cbk][r] + bqkv[colbase + cbk * 16 + lr];
    __syncthreads();

    if (which < 2) {
        const int er = tid >> 2;
        const int eu = tid & 3;
        const int n = rb * 64 + er;
        if (n < N_TOK) {
            float outv[16];
            const bool is_img = (n < HW_IMG);
            int ts = 0, tj = 0;
            if (!is_img) { const int m = n - HW_IMG; ts = m / NT_TOK; tj = m - ts * NT_TOK; }

            if (is_img) {
                const float p = (eu < 2) ? pos2d[2 * n] : pos2d[2 * n + 1];
                const bool lowhalf = ((eu & 1) == 0);
                #pragma unroll
                for (int dd = 0; dd < 16; ++dd) {
                    const int d = (eu << 4) + dd;
                    float sv, cv;
                    sincosf(p * expf((float)dd * -0.28782313662425574f), &sv, &cv);
                    const float rot = lowhalf ? -Ct[er][d + 16] : Ct[er][d - 16];
                    outv[dd] = Ct[er][d] * cv + rot * sv;
                }
            } else if (tj < HW_IMG) {
                #pragma unroll
                for (int dd = 0; dd < 16; ++dd) {
                    const int d = (eu << 4) + dd;
                    float val = Ct[er][d];
                    if (d < 30) {
                        const int g = d / 3;
                        const float* R = tposes + ts * 16 + (d - g * 3) * 4;
                        val = R[0] * Ct[er][g * 3] + R[1] * Ct[er][g * 3 + 1] + R[2] * Ct[er][g * 3 + 2];
                    }
                    outv[dd] = val;
                }
            } else {
                #pragma unroll
                for (int dd = 0; dd < 16; ++dd) outv[dd] = Ct[er][(eu << 4) + dd];
            }

            const float scale = (which == 0) ? 0.125f : 1.0f;
            u16x8 h0, h1, l0v, l1v;
            #pragma unroll
            for (int j = 0; j < 8; ++j) { u16 hh, ll; split1(outv[j] * scale, hh, ll); h0[j] = hh; l0v[j] = ll; }
            #pragma unroll
            for (int j = 0; j < 8; ++j) { u16 hh, ll; split1(outv[8 + j] * scale, hh, ll); h1[j] = hh; l1v[j] = ll; }
            u16* dh = (which == 0 ? Qhi : Khi) + ((size_t)h * N_TOK + n) * HD + (eu << 4);
            u16* dl = (which == 0 ? Qlo : Klo) + ((size_t)h * N_TOK + n) * HD + (eu << 4);
            *(u16x8*)dh = h0;  *(u16x8*)(dh + 8) = h1;
            *(u16x8*)dl = l0v; *(u16x8*)(dl + 8) = l1v;
        }
    } else {
        // V: write transposed planes [h][d][token]
        const int vd_ = tid >> 2, vch = (tid & 3) << 4;
        const int tokbase = rb * 64 + vch;
        u16 th[16], tl[16];
        #pragma unroll
        for (int j = 0; j < 16; ++j) { u16 hh, ll; split1(Ct[vch + j][vd_], hh, ll); th[j] = hh; tl[j] = ll; }
        u16* dh = Vthi + (size_t)(h * HD + vd_) * NVP + tokbase;
        u16* dl = Vtlo + (size_t)(h * HD + vd_) * NVP + tokbase;
        if (tokbase + 16 <= N_TOK) {
            *(u16x8*)dh = *(u16x8*)&th[0];  *(u16x8*)(dh + 8) = *(u16x8*)&th[8];
            *(u16x8*)dl = *(u16x8*)&tl[0];  *(u16x8*)(dl + 8) = *(u16x8*)&tl[8];
        } else {
            #pragma unroll
            for (int j = 0; j < 16; ++j)
                if (tokbase + j < N_TOK) { dh[j] = th[j]; dl[j] = tl[j]; }
        }
    }
}

// ---------------- Kernel 2: MFMA hi/lo flash attention (plane inputs) ----------------
__global__ __launch_bounds__(256)
void attn_mfma(const u16* __restrict__ Qhi, const u16* __restrict__ Qlo,
               const u16* __restrict__ Khi, const u16* __restrict__ Klo,
               const u16* __restrict__ Vthi, const u16* __restrict__ Vtlo,
               u16* __restrict__ Ohi, u16* __restrict__ Olo)
{
    __shared__ __align__(16) u16 Kh_s[64][64], Kl_s[64][64], Vh_s[64][64], Vl_s[64][64];
    __shared__ __align__(16) unsigned int P2[64][64];

    const int head = blockIdx.y;
    const int qb = blockIdx.x;
    const int tid = threadIdx.x;
    const int w = tid >> 6, l = tid & 63;
    const int lr = l & 15, lg = l >> 4;

    // Q fragments (pre-scaled in qkv_mfma)
    bf16x8 qh_[2], ql_[2];
    {
        int row = qb * 64 + w * 16 + lr;
        if (row >= N_TOK) row = N_TOK - 1;
        const u16* qph = Qhi + ((size_t)head * N_TOK + row) * HD;
        const u16* qpl = Qlo + ((size_t)head * N_TOK + row) * HD;
        #pragma unroll
        for (int ks = 0; ks < 2; ++ks) {
            qh_[ks] = *(const bf16x8*)(qph + ks * 32 + lg * 8);
            ql_[ks] = *(const bf16x8*)(qpl + ks * 32 + lg * 8);
        }
    }

    float m0[4] = {-1e30f, -1e30f, -1e30f, -1e30f};
    float l0[4] = {0.f, 0.f, 0.f, 0.f};
    f32x4 acc[4];
    #pragma unroll
    for (int db = 0; db < 4; ++db) acc[db] = (f32x4){0.f, 0.f, 0.f, 0.f};

    const int skey = tid >> 2, sch = (tid & 3) << 4;
    const int vd_ = tid >> 2, vch = (tid & 3) << 4;
    const int swk = (skey & 7) << 3;
    const int swv = (vd_ & 7) << 3;
    const int swf = (lr & 7) << 3;     // frag-read swizzle (K and V rows)
    const int swa = (lr & 7) << 2;     // P2 A-read swizzle
    const size_t vrowbase = (size_t)(head * HD + vd_) * NVP;

    const int NTILE = (N_TOK + 63) / 64;
    for (int kt = 0; kt < NTILE; ++kt) {
        const int kbase = kt << 6;

        // issue global loads before barrier (hide latency under prior PV)
        int krow = kbase + skey;
        if (krow >= N_TOK) krow = N_TOK - 1;
        const u16* kph = Khi + ((size_t)head * N_TOK + krow) * HD + sch;
        const u16* kpl = Klo + ((size_t)head * N_TOK + krow) * HD + sch;
        const u16x8 k0h = *(const u16x8*)kph;
        const u16x8 k1h = *(const u16x8*)(kph + 8);
        const u16x8 k0l = *(const u16x8*)kpl;
        const u16x8 k1l = *(const u16x8*)(kpl + 8);
        u16x8 v0h, v1h, v0l, v1l;
        if (kbase + vch + 16 <= N_TOK) {
            const u16* vph = Vthi + vrowbase + kbase + vch;
            const u16* vpl = Vtlo + vrowbase + kbase + vch;
            v0h = *(const u16x8*)vph;  v1h = *(const u16x8*)(vph + 8);
            v0l = *(const u16x8*)vpl;  v1l = *(const u16x8*)(vpl + 8);
        } else {
            #pragma unroll
            for (int j = 0; j < 8; ++j) {
                int ka = kbase + vch + j;     if (ka >= N_TOK) ka = N_TOK - 1;
                int kb = kbase + vch + 8 + j; if (kb >= N_TOK) kb = N_TOK - 1;
                v0h[j] = Vthi[vrowbase + ka]; v1h[j] = Vthi[vrowbase + kb];
                v0l[j] = Vtlo[vrowbase + ka]; v1l[j] = Vtlo[vrowbase + kb];
            }
        }

        __syncthreads();   // prev tile fully consumed
        *(u16x8*)&Kh_s[skey][(sch + 0) ^ swk] = k0h;
        *(u16x8*)&Kh_s[skey][(sch + 8) ^ swk] = k1h;
        *(u16x8*)&Kl_s[skey][(sch + 0) ^ swk] = k0l;
        *(u16x8*)&Kl_s[skey][(sch + 8) ^ swk] = k1l;
        *(u16x8*)&Vh_s[vd_][(vch + 0) ^ swv] = v0h;
        *(u16x8*)&Vh_s[vd_][(vch + 8) ^ swv] = v1h;
        *(u16x8*)&Vl_s[vd_][(vch + 0) ^ swv] = v0l;
        *(u16x8*)&Vl_s[vd_][(vch + 8) ^ swv] = v1l;
        __syncthreads();

        // ---- S = Q K^T ----
        f32x4 s[4];
        #pragma unroll
        for (int kb = 0; kb < 4; ++kb) {
            s[kb] = (f32x4){0.f, 0.f, 0.f, 0.f};
            const int key = kb * 16 + lr;
            #pragma unroll
            for (int ks = 0; ks < 2; ++ks) {
                const int koff = (ks * 32 + lg * 8) ^ swf;
                const bf16x8 bh = *(const bf16x8*)&Kh_s[key][koff];
                const bf16x8 bl = *(const bf16x8*)&Kl_s[key][koff];
                s[kb] = __builtin_amdgcn_mfma_f32_16x16x32_bf16(qh_[ks], bh, s[kb], 0, 0, 0);
                s[kb] = __builtin_amdgcn_mfma_f32_16x16x32_bf16(qh_[ks], bl, s[kb], 0, 0, 0);
                s[kb] = __builtin_amdgcn_mfma_f32_16x16x32_bf16(ql_[ks], bh, s[kb], 0, 0, 0);
            }
        }

        if (kbase + 64 > N_TOK) {
            #pragma unroll
            for (int kb = 0; kb < 4; ++kb)
                if (kbase + kb * 16 + lr >= N_TOK) {
                    #pragma unroll
                    for (int r = 0; r < 4; ++r) s[kb][r] = -1e30f;
                }
        }

        // ---- online softmax ----
        float mt[4], al[4];
        #pragma unroll
        for (int r = 0; r < 4; ++r)
            mt[r] = fmaxf(fmaxf(s[0][r], s[1][r]), fmaxf(s[2][r], s[3][r]));
        #pragma unroll
        for (int r = 0; r < 4; ++r) {
            mt[r] = fmaxf(mt[r], __shfl_xor(mt[r], 1));
            mt[r] = fmaxf(mt[r], __shfl_xor(mt[r], 2));
            mt[r] = fmaxf(mt[r], __shfl_xor(mt[r], 4));
            mt[r] = fmaxf(mt[r], __shfl_xor(mt[r], 8));
        }
        #pragma unroll
        for (int r = 0; r < 4; ++r) {
            const float mn = fmaxf(m0[r], mt[r]);
            al[r] = __expf(m0[r] - mn);
            m0[r] = mn;
        }
        #pragma unroll
        for (int kb = 0; kb < 4; ++kb)
            #pragma unroll
            for (int r = 0; r < 4; ++r)
                s[kb][r] = __expf(s[kb][r] - m0[r]);
        #pragma unroll
        for (int r = 0; r < 4; ++r)
            l0[r] = l0[r] * al[r] + (s[0][r] + s[1][r] + s[2][r] + s[3][r]);
        #pragma unroll
        for (int db = 0; db < 4; ++db)
            #pragma unroll
            for (int r = 0; r < 4; ++r) acc[db][r] *= al[r];

        // ---- pack P hi/lo -> LDS ----
        #pragma unroll
        for (int r = 0; r < 4; ++r) {
            const int rw = w * 16 + lg * 4 + r;
            const int swp = (rw & 7) << 2;
            #pragma unroll
            for (int kb = 0; kb < 4; ++kb) {
                const float p = s[kb][r];
                u16 ph, pl;
                split1(p, ph, pl);
                P2[rw][(kb * 16 + lr) ^ swp] = (unsigned)ph | ((unsigned)pl << 16);
            }
        }
        __syncthreads();

        // ---- PV ----
        const int arow = w * 16 + lr;
        #pragma unroll
        for (int ks = 0; ks < 2; ++ks) {
            const int kb8 = ks * 32 + lg * 8;
            const u32x4 pa = *(const u32x4*)&P2[arow][(kb8 + 0) ^ swa];
            const u32x4 pb = *(const u32x4*)&P2[arow][(kb8 + 4) ^ swa];
            bf16x8 ph, pl;
            #pragma unroll
            for (int e = 0; e < 4; ++e) {
                ph[e]     = (short)(pa[e] & 0xffffu);
                pl[e]     = (short)(pa[e] >> 16);
                ph[4 + e] = (short)(pb[e] & 0xffffu);
                pl[4 + e] = (short)(pb[e] >> 16);
            }
            #pragma unroll
            for (int db = 0; db < 4; ++db) {
                const int vr = db * 16 + lr;
                const int koff = kb8 ^ swf;
                const bf16x8 vh = *(const bf16x8*)&Vh_s[vr][koff];
                const bf16x8 vl = *(const bf16x8*)&Vl_s[vr][koff];
                acc[db] = __builtin_amdgcn_mfma_f32_16x16x32_bf16(ph, vh, acc[db], 0, 0, 0);
                acc[db] = __builtin_amdgcn_mfma_f32_16x16x32_bf16(ph, vl, acc[db], 0, 0, 0);
                acc[db] = __builtin_amdgcn_mfma_f32_16x16x32_bf16(pl, vh, acc[db], 0, 0, 0);
            }
        }
    }

    // ---- epilogue: normalize, split, write O planes ----
    #pragma unroll
    for (int r = 0; r < 4; ++r) {
        l0[r] += __shfl_xor(l0[r], 1);
        l0[r] += __shfl_xor(l0[r], 2);
        l0[r] += __shfl_xor(l0[r], 4);
        l0[r] += __shfl_xor(l0[r], 8);
    }
    const int orow0 = qb * 64 + w * 16 + lg * 4;
    #pragma unroll
    for (int r = 0; r < 4; ++r) {
        const int row = orow0 + r;
        if (row < N_TOK) {
            const float inv = 1.0f / l0[r];
            #pragma unroll
            for (int db = 0; db < 4; ++db) {
                u16 hh, ll;
                split1(acc[db][r] * inv, hh, ll);
                const size_t o = (size_t)row * CDIM + head * HD + db * 16 + lr;
                Ohi[o] = hh;
                Olo[o] = ll;
            }
        }
    }
}

// ---------------- Kernel 3: output projection via MFMA hi/lo ----------------
__global__ __launch_bounds__(256)
void proj_mfma(const u16* __restrict__ Ahi, const u16* __restrict__ Alo,
               const u16* __restrict__ Whi, const u16* __restrict__ Wlo,
               const float* __restrict__ bp, float* __restrict__ out)
{
    __shared__ __align__(16) u16 Ah[64][64], Al[64][64], Bh[64][64], Bl[64][64];

    const int rb = blockIdx.x;
    const int colbase = blockIdx.y * 64;
    const int tid = threadIdx.x;
    const int w = tid >> 6, l = tid & 63;
    const int lr = l & 15, lg = l >> 4;

    const int srow = tid >> 2, sch = (tid & 3) << 4;
    int arow = rb * 64 + srow;
    if (arow >= N_TOK) arow = N_TOK - 1;
    const size_t abase = (size_t)arow * CDIM + sch;
    const size_t bbase = (size_t)(colbase + srow) * CDIM + sch;

    f32x4 acc[4];
    #pragma unroll
    for (int i = 0; i < 4; ++i) acc[i] = (f32x4){0.f, 0.f, 0.f, 0.f};

    const int sw = (srow & 7) << 3;
    const int swf = (lr & 7) << 3;

    for (int k0 = 0; k0 < CDIM; k0 += 64) {
        const u16x8 a0h = *(const u16x8*)(Ahi + abase + k0);
        const u16x8 a1h = *(const u16x8*)(Ahi + abase + k0 + 8);
        const u16x8 a0l = *(const u16x8*)(Alo + abase + k0);
        const u16x8 a1l = *(const u16x8*)(Alo + abase + k0 + 8);
        const u16x8 b0h = *(const u16x8*)(Whi + bbase + k0);
        const u16x8 b1h = *(const u16x8*)(Whi + bbase + k0 + 8);
        const u16x8 b0l = *(const u16x8*)(Wlo + bbase + k0);
        const u16x8 b1l = *(const u16x8*)(Wlo + bbase + k0 + 8);
        __syncthreads();
        *(u16x8*)&Ah[srow][(sch + 0) ^ sw] = a0h;
        *(u16x8*)&Ah[srow][(sch + 8) ^ sw] = a1h;
        *(u16x8*)&Al[srow][(sch + 0) ^ sw] = a0l;
        *(u16x8*)&Al[srow][(sch + 8) ^ sw] = a1l;
        *(u16x8*)&Bh[srow][(sch + 0) ^ sw] = b0h;
        *(u16x8*)&Bh[srow][(sch + 8) ^ sw] = b1h;
        *(u16x8*)&Bl[srow][(sch + 0) ^ sw] = b0l;
        *(u16x8*)&Bl[srow][(sch + 8) ^ sw] = b1l;
        __syncthreads();
        #pragma unroll
        for (int ks = 0; ks < 2; ++ks) {
            const int koff = (ks * 32 + lg * 8) ^ swf;
            const bf16x8 ah_ = *(const bf16x8*)&Ah[w * 16 + lr][koff];
            const bf16x8 al_ = *(const bf16x8*)&Al[w * 16 + lr][koff];
            #pragma unroll
            for (int cbk = 0; cbk < 4; ++cbk) {
                const bf16x8 bh_ = *(const bf16x8*)&Bh[cbk * 16 + lr][koff];
                const bf16x8 bl_ = *(const bf16x8*)&Bl[cbk * 16 + lr][koff];
                acc[cbk] = __builtin_amdgcn_mfma_f32_16x16x32_bf16(ah_, bh_, acc[cbk], 0, 0, 0);
                acc[cbk] = __builtin_amdgcn_mfma_f32_16x16x32_bf16(ah_, bl_, acc[cbk], 0, 0, 0);
                acc[cbk] = __builtin_amdgcn_mfma_f32_16x16x32_bf16(al_, bh_, acc[cbk], 0, 0, 0);
            }
        }
    }

    #pragma unroll
    for (int cbk = 0; cbk < 4; ++cbk) {
        const float bb = bp[colbase + cbk * 16 + lr];
        #pragma unroll
        for (int r = 0; r < 4; ++r) {
            const int row = rb * 64 + w * 16 + lg * 4 + r;
            if (row < N_TOK)
                out[(size_t)row * CDIM + colbase + cbk * 16 + lr] = acc[cbk][r] + bb;
        }
    }
}

extern "C" void kernel_launch(void* const* d_in, const int* in_sizes, int n_in,
                              void* d_out, int out_size, void* d_ws, size_t ws_size,
                              hipStream_t stream)
{
    const float* q_tokens = (const float*)d_in[0];
    const float* t_tokens = (const float*)d_in[1];
    const float* pos2d    = (const float*)d_in[2];
    const float* tposes   = (const float*)d_in[3];
    const float* Wqkv     = (const float*)d_in[4];
    const float* bqkv     = (const float*)d_in[5];
    const float* Wproj    = (const float*)d_in[6];
    const float* bproj    = (const float*)d_in[7];
    float* out = (float*)d_out;

    const size_t PQ = (size_t)NH * N_TOK * HD;    // 2,214,912
    const size_t PV = (size_t)NH * HD * NVP;      // 2,217,984
    const size_t PX = (size_t)N_TOK * CDIM;       // 2,214,912
    const size_t PW = (size_t)QKV_COLS * CDIM;    // 1,769,472

    u16* base = (u16*)d_ws;
    u16* Qhi  = base;
    u16* Qlo  = Qhi + PQ;
    u16* Khi  = Qlo + PQ;
    u16* Klo  = Khi + PQ;
    u16* Vthi = Klo + PQ;
    u16* Vtlo = Vthi + PV;
    u16* XOhi = Vtlo + PV;     // x planes, later reused as O planes
    u16* XOlo = XOhi + PX;
    u16* WThi = XOlo + PX;     // Wqkv^T planes, later reused for Wproj^T
    u16* WTlo = WThi + PW;

    conv_x<<<dim3((N_TOK * CDIM / 4 + 255) / 256), 256, 0, stream>>>(q_tokens, t_tokens, XOhi, XOlo);
    conv_wT<<<dim3(CDIM / 64, QKV_COLS / 64), 256, 0, stream>>>(Wqkv, QKV_COLS, WThi, WTlo);

    dim3 g1((N_TOK + 63) / 64, 36);
    qkv_mfma<<<g1, 256, 0, stream>>>(XOhi, XOlo, WThi, WTlo, bqkv, pos2d, tposes,
                                     Qhi, Qlo, Khi, Klo, Vthi, Vtlo);

    conv_wT<<<dim3(CDIM / 64, CDIM / 64), 256, 0, stream>>>(Wproj, CDIM, WThi, WTlo);

    dim3 g2((N_TOK + 63) / 64, NH);
    attn_mfma<<<g2, 256, 0, stream>>>(Qhi, Qlo, Khi, Klo, Vthi, Vtlo, XOhi, XOlo);

    dim3 g3((N_TOK + 63) / 64, CDIM / 64);
    proj_mfma<<<g3, 256, 0, stream>>>(XOhi, XOlo, WThi, WTlo, bproj, out);
}